// Round 5
// baseline (4826.439 us; speedup 1.0000x reference)
//
#include <hip/hip_runtime.h>

#define Tn 1024
#define Fn 64
#define Un 256
#define Gn 1024
#define THREADS 512
#define NB 32        // one block per 16-row batch group — ZERO cross-block comms
#define ASB 272      // A_s (h, int8) row stride bytes: 256 + 16 pad (bank-skew)
#define XSW 72       // xs (x, bf16) row stride ushorts: 64 + 8 pad

typedef __attribute__((ext_vector_type(8))) short bf16x8;
typedef __attribute__((ext_vector_type(8))) unsigned short ushort8;
typedef __attribute__((ext_vector_type(4))) float f32x4;
typedef __attribute__((ext_vector_type(4))) int i32x4;

// ws layout (bytes): hdr 4K | Up (i8 Uh, 8*1024*4*8 = 256K) | Wp (bf16 W,
// 2*1024*4*8*2 = 128K) | Su (f32[1024]) | Bb (f32[1024])
#define WS_UP 4096
#define WS_WP (WS_UP + 262144)
#define WS_SU (WS_WP + 131072)
#define WS_BB (WS_SU + 4096)

__device__ __forceinline__ float bf2f(unsigned short u){
  union { unsigned int i; float f; } v; v.i = ((unsigned int)u) << 16; return v.f;
}
__device__ __forceinline__ unsigned short f2bf(float f){
  unsigned int u = __float_as_uint(f);
  u += 0x7FFFu + ((u >> 16) & 1u);
  return (unsigned short)(u >> 16);
}
__device__ __forceinline__ float load_f(const void* p, long idx, int isf32){
  if (isf32) return ((const float*)p)[idx];
  return bf2f(((const unsigned short*)p)[idx]);
}
__device__ __forceinline__ float sigm(float x){ return 1.0f / (1.0f + __expf(-x)); }
__device__ __forceinline__ float tanh_f(float x){ return 2.0f * sigm(2.0f * x) - 1.0f; }

// ---------------------------------------------------------------------------
__global__ void init_k(const void* x, int* wsi){
  int tid = threadIdx.x;
  if (tid < 64){
    int cnt = 0;
    for (int s2 = 0; s2 < 4; ++s2){
      float v = bf2f(((const unsigned short*)x)[tid + 64*s2]);
      if (!(fabsf(v) <= 100.0f)) cnt++;
    }
    for (int off = 32; off > 0; off >>= 1) cnt += __shfl_down(cnt, off);
    if (tid == 0) wsi[0] = (cnt > 32) ? 1 : 0;   // 1 => inputs are fp32
  }
}

// ---------------------------------------------------------------------------
// Column permutation shared by all packers / the LSTM kernel:
//   col = g*256 + wv*32 + hh*16 + l15,  nt = hh*4 + g,  n_p = wv*128 + nt*16 + l15
// Fragment element j of (kt, n_p, q) <-> K-row k = kt*32 + q*8 + j (the
// verified bf16 16x16x32 B-layout; i8 16x16x32 uses the same 8-contiguous-K
// per-lane mapping).

// Per-column absmax scales + int8 quantization of Uh (K=256 -> 8 k-tiles).
__global__ void scales_k(const void* Uh, const void* bvec, char* Up,
                         float* Su_c, float* Bb_c, const int* dt){
  int isf32 = *dt;
  int col = blockIdx.x * blockDim.x + threadIdx.x;
  if (col >= 1024) return;
  float su = 1e-20f;
  for (int k = 0; k < 256; ++k)
    su = fmaxf(su, fabsf(load_f(Uh, (long)k*Gn + col, isf32)));
  float r = 127.f / su;
  int g = col >> 8, rem = col & 255, wv = rem >> 5, r2 = rem & 31;
  int hh = r2 >> 4, l15v = r2 & 15;
  int nt = hh*4 + g;
  int n_p = wv*128 + nt*16 + l15v;
  for (int k = 0; k < 256; ++k){
    int kt = k >> 5, q = (k >> 3) & 3, j = k & 7;
    float v = rintf(load_f(Uh, (long)k*Gn + col, isf32) * r);
    v = fminf(fmaxf(v, -127.f), 127.f);
    Up[(long)(((kt*1024 + n_p)*4 + q)*8 + j)] = (char)(int)v;
  }
  Su_c[col] = su / (127.f * 127.f);   // dequant: z_h = Su * (sum uq*hq)
  Bb_c[col] = load_f(bvec, col, isf32);
}

// Pack W (K=64 -> 2 bf16 k-tiles) into B-fragment order (streamed from L2).
__global__ void wp_k(const void* W, unsigned short* Wp, const int* dt){
  int isf32 = *dt;
  int gidx = blockIdx.x * blockDim.x + threadIdx.x;   // = (kt*1024 + n_p)*4 + q
  if (gidx >= 8192) return;
  int kt = gidx >> 12, rem = gidx & 4095, n_p = rem >> 2, q = rem & 3;
  int wv = n_p >> 7, nt = (n_p >> 4) & 7, l15v = n_p & 15;
  int col = (nt & 3)*256 + wv*32 + (nt >> 2)*16 + l15v;
  unsigned short vals[8];
  #pragma unroll
  for (int j = 0; j < 8; ++j){
    int k = kt*32 + q*8 + j;
    vals[j] = f2bf(load_f(W, (long)k*Gn + col, isf32));
  }
  *(ushort8*)(Wp + (long)gidx * 8) = *(ushort8*)vals;
}

// ---------------------------------------------------------------------------
// Persistent LSTM, 32 blocks x 512 threads (8 waves), ONE block per group.
// Rounds 0-4 proved the cross-CU h-exchange is a ~4500cy structural floor
// invariant to mechanism/topology — so it is eliminated: Uh lives int8
// (per-col scales) in VGPRs (wfh[8][8] longs = 128/wave), h recurrence is
// LDS-only with a single barrier per step. The x contribution zx(t+1) =
// x_{t+1}@W + b is computed ONE STEP AHEAD in exact bf16 MFMA into persistent
// f32 accumulators (producer C-layout == consumer layout), W streamed from L2.
__global__ __launch_bounds__(THREADS, 2) void lstm_k(
    const void* x, const void* dense_w, const void* dense_b,
    const char* Up, const unsigned short* Wp,
    const float* Su_g, const float* Bb_g, const int* dt, void* out)
{
  __shared__ __align__(16) char A_s[2][16*ASB];        // h, int8, dbuf
  __shared__ __align__(16) unsigned short xs[2][16*XSW]; // x rows, bf16, dbuf
  __shared__ float Su_s[1024];
  __shared__ float Bb_s[1024];
  __shared__ float outv[16];

  const int isf32 = *dt;
  const int tid = threadIdx.x;
  const int wv  = tid >> 6;       // wave 0..7 (owns cols wv*32.. per gate)
  const int l   = tid & 63;
  const int l15 = l & 15;
  const int q   = l >> 4;
  const int gb  = blockIdx.x;     // batch group: rows gb*16..+16

  // ---- Uh int8 fragments into registers: wfh[kt][nt] (128 VGPR) ----
  long wfh[8][8];
  #pragma unroll
  for (int kt = 0; kt < 8; ++kt)
    #pragma unroll
    for (int nt = 0; nt < 8; ++nt)
      wfh[kt][nt] = *(const long*)(Up +
          (long)(((kt*1024 + wv*128 + nt*16 + l15)*4 + q)*8));

  // ---- prologue: consts -> LDS, zero h buffer 0, stage x(0), x(1) ----
  for (int i = tid; i < 1024; i += THREADS){ Su_s[i] = Su_g[i]; Bb_s[i] = Bb_g[i]; }
  for (int i = tid; i < 16*ASB; i += THREADS) A_s[0][i] = 0;
  for (int tt = 0; tt < 2; ++tt){
    if (tid < 128){
      int m = tid >> 3, seg = tid & 7;
      long src = ((long)(gb*16 + m)*Tn + tt)*Fn + seg*8;
      unsigned short v[8];
      if (isf32){ for (int j = 0; j < 8; ++j) v[j] = f2bf(((const float*)x)[src + j]); }
      else      { *(ushort8*)v = *(const ushort8*)((const unsigned short*)x + src); }
      *(ushort8*)&xs[tt][m*XSW + seg*8] = *(ushort8*)v;
    }
  }
  __syncthreads();

  // ---- zx(0) = x_0 @ W + b (bias folded into acc init) ----
  f32x4 accz[8];
  #pragma unroll
  for (int nt = 0; nt < 8; ++nt){
    float bb = Bb_s[(nt & 3)*256 + wv*32 + (nt >> 2)*16 + l15];
    accz[nt] = (f32x4){bb, bb, bb, bb};
  }
  #pragma unroll
  for (int kt2 = 0; kt2 < 2; ++kt2){
    bf16x8 afx = *(const bf16x8*)&xs[0][l15*XSW + kt2*32 + q*8];
    #pragma unroll
    for (int nt = 0; nt < 8; ++nt){
      bf16x8 wfx = *(const bf16x8*)(Wp +
          (long)(((kt2*1024 + wv*128 + nt*16 + l15)*4 + q)*8));
      accz[nt] = __builtin_amdgcn_mfma_f32_16x16x32_bf16(afx, wfx, accz[nt], 0, 0, 0);
    }
  }

  float c_st[8] = {0.f,0.f,0.f,0.f,0.f,0.f,0.f,0.f};

  for (int t = 0; t < Tn; ++t){
    const int buf = t & 1, nbuf = buf ^ 1;

    // (1) x(t+2) global -> regs (consumed at stage (4))
    unsigned short xv[8];
    if (tid < 128 && (t+2) < Tn){
      int m = tid >> 3, seg = tid & 7;
      long src = ((long)(gb*16 + m)*Tn + (t+2))*Fn + seg*8;
      if (isf32){ for (int j = 0; j < 8; ++j) xv[j] = f2bf(((const float*)x)[src + j]); }
      else      { *(ushort8*)xv = *(const ushort8*)((const unsigned short*)x + src); }
    }

    // (2) per-hh half: int8 h-MFMA then gates (keeps live acc regs at 16)
    #pragma unroll
    for (int hh = 0; hh < 2; ++hh){
      i32x4 acch[4];
      #pragma unroll
      for (int gg = 0; gg < 4; ++gg) acch[gg] = (i32x4){0,0,0,0};
      #pragma unroll
      for (int kt = 0; kt < 8; ++kt){
        long af = *(const long*)&A_s[buf][l15*ASB + kt*32 + q*8];
        #pragma unroll
        for (int gg = 0; gg < 4; ++gg)
          acch[gg] = __builtin_amdgcn_mfma_i32_16x16x32_i8(
              af, wfh[kt][hh*4 + gg], acch[gg], 0, 0, 0);
      }
      float Su4[4];
      #pragma unroll
      for (int gg = 0; gg < 4; ++gg)
        Su4[gg] = Su_s[gg*256 + wv*32 + hh*16 + l15];
      #pragma unroll
      for (int r = 0; r < 4; ++r){
        float zi = Su4[0]*(float)acch[0][r] + accz[hh*4 + 0][r];
        float zf = Su4[1]*(float)acch[1][r] + accz[hh*4 + 1][r];
        float zg = Su4[2]*(float)acch[2][r] + accz[hh*4 + 2][r];
        float zo = Su4[3]*(float)acch[3][r] + accz[hh*4 + 3][r];
        float ig = sigm(zi), fg = sigm(zf), gt = tanh_f(zg), og = sigm(zo);
        float cn = fg*c_st[hh*4 + r] + ig*gt;
        c_st[hh*4 + r] = cn;
        float hv = og * tanh_f(cn);
        float hq = fminf(fmaxf(rintf(hv * 127.f), -127.f), 127.f);
        A_s[nbuf][(q*4 + r)*ASB + wv*32 + hh*16 + l15] = (char)(int)hq;
      }
    }

    // (3) zx(t+1) = x_{t+1} @ W + b — exact bf16, into the freed accz regs
    if (t + 1 < Tn){
      const int p = (t + 1) & 1;
      #pragma unroll
      for (int nt = 0; nt < 8; ++nt){
        float bb = Bb_s[(nt & 3)*256 + wv*32 + (nt >> 2)*16 + l15];
        accz[nt] = (f32x4){bb, bb, bb, bb};
      }
      #pragma unroll
      for (int kt2 = 0; kt2 < 2; ++kt2){
        bf16x8 afx = *(const bf16x8*)&xs[p][l15*XSW + kt2*32 + q*8];
        #pragma unroll
        for (int nt = 0; nt < 8; ++nt){
          bf16x8 wfx = *(const bf16x8*)(Wp +
              (long)(((kt2*1024 + wv*128 + nt*16 + l15)*4 + q)*8));
          accz[nt] = __builtin_amdgcn_mfma_f32_16x16x32_bf16(afx, wfx, accz[nt], 0, 0, 0);
        }
      }
    }

    // (4) stage x(t+2) into xs[(t+2)&1] (parity-disjoint from (3)'s reads)
    if (tid < 128 && (t+2) < Tn){
      int m = tid >> 3, seg = tid & 7;
      *(ushort8*)&xs[(t+2) & 1][m*XSW + seg*8] = *(ushort8*)xv;
    }
    __syncthreads();   // single barrier: h(t+1) + x(t+2) visible
  }

  // ---- epilogue: attention with s-dim==1 collapses to out = sigm(h_T.dw+db) ----
  {
    int m = tid >> 5, j = tid & 31;
    float partial = 0.f;
    for (int u = j; u < 256; u += 32)
      partial += (float)(int)((signed char)A_s[0][m*ASB + u]) *
                 load_f(dense_w, u, isf32);
    #pragma unroll
    for (int off = 1; off < 32; off <<= 1) partial += __shfl_xor(partial, off);
    if (j == 0)
      outv[m] = sigm(partial * (1.f/127.f) + load_f(dense_b, 0, isf32));
  }
  __syncthreads();
  for (int mm = 0; mm < 16; ++mm){
    float v = outv[mm];
    long base = (long)(gb*16 + mm) * Tn;
    for (int col2 = tid; col2 < Tn; col2 += THREADS){
      if (isf32) ((float*)out)[base + col2] = v;
      else       ((unsigned short*)out)[base + col2] = f2bf(v);
    }
  }
}

// ---------------------------------------------------------------------------
extern "C" void kernel_launch(void* const* d_in, const int* in_sizes, int n_in,
                              void* d_out, int out_size, void* d_ws, size_t ws_size,
                              hipStream_t stream){
  const void* x  = d_in[0];
  const void* W  = d_in[1];
  const void* Uh = d_in[2];
  const void* b  = d_in[3];
  const void* dw = d_in[4];
  const void* db = d_in[5];

  int* hdr = (int*)d_ws;
  char* Up = (char*)d_ws + WS_UP;
  unsigned short* Wp = (unsigned short*)((char*)d_ws + WS_WP);
  float* Su = (float*)((char*)d_ws + WS_SU);
  float* Bb = (float*)((char*)d_ws + WS_BB);

  init_k<<<1, 64, 0, stream>>>(x, hdr);
  scales_k<<<4, 256, 0, stream>>>(Uh, b, Up, Su, Bb, hdr);
  wp_k<<<32, 256, 0, stream>>>(W, Wp, hdr);
  lstm_k<<<NB, THREADS, 0, stream>>>(x, dw, db, Up, Wp, Su, Bb, hdr, d_out);
}

// Round 6
// 4590.505 us; speedup vs baseline: 1.0514x; 1.0514x over previous
//
#include <hip/hip_runtime.h>

#define Tn 1024
#define Fn 64
#define Un 256
#define Gn 1024
#define THREADS 512
#define NB 32        // one block per 16-row batch group — ZERO cross-block comms
#define ASB 272      // A_s (h, int8) row stride bytes: 256 + 16 pad (bank-skew)
#define XSW 72       // xs (x, bf16) row stride ushorts: 64 + 8 pad

typedef __attribute__((ext_vector_type(8))) short bf16x8;
typedef __attribute__((ext_vector_type(8))) unsigned short ushort8;
typedef __attribute__((ext_vector_type(4))) float f32x4;
typedef __attribute__((ext_vector_type(4))) int i32x4;

// ws layout (bytes): hdr 4K | Up (i8 Uh, 8*1024*4*8 = 256K) | Wp (bf16 W,
// 2*1024*4*8*2 = 128K) | Su (f32[1024]) | Bb (f32[1024])
#define WS_UP 4096
#define WS_WP (WS_UP + 262144)
#define WS_SU (WS_WP + 131072)
#define WS_BB (WS_SU + 4096)

__device__ __forceinline__ float bf2f(unsigned short u){
  union { unsigned int i; float f; } v; v.i = ((unsigned int)u) << 16; return v.f;
}
__device__ __forceinline__ unsigned short f2bf(float f){
  unsigned int u = __float_as_uint(f);
  u += 0x7FFFu + ((u >> 16) & 1u);
  return (unsigned short)(u >> 16);
}
__device__ __forceinline__ float load_f(const void* p, long idx, int isf32){
  if (isf32) return ((const float*)p)[idx];
  return bf2f(((const unsigned short*)p)[idx]);
}
// v_rcp_f32 (~1e-5 rel err) instead of IEEE divide: the round-5 post-mortem
// showed 1.0f/(1.0f+e) expands to the ~10-instr v_div_* sequence, and with
// 5 of them per LSTM cell x 8 cells/thread it WAS the critical path (68%
// active-CU VALUBusy). Tolerance is bf16-output level — rcp is plenty.
__device__ __forceinline__ float rcp_f(float x){ return __builtin_amdgcn_rcpf(x); }
__device__ __forceinline__ float sigm(float x){ return rcp_f(1.0f + __expf(-x)); }
__device__ __forceinline__ float tanh_f(float x){ return 2.0f * sigm(2.0f * x) - 1.0f; }

// ---------------------------------------------------------------------------
__global__ void init_k(const void* x, int* wsi){
  int tid = threadIdx.x;
  if (tid < 64){
    int cnt = 0;
    for (int s2 = 0; s2 < 4; ++s2){
      float v = bf2f(((const unsigned short*)x)[tid + 64*s2]);
      if (!(fabsf(v) <= 100.0f)) cnt++;
    }
    for (int off = 32; off > 0; off >>= 1) cnt += __shfl_down(cnt, off);
    if (tid == 0) wsi[0] = (cnt > 32) ? 1 : 0;   // 1 => inputs are fp32
  }
}

// ---------------------------------------------------------------------------
// Column permutation shared by all packers / the LSTM kernel:
//   col = g*256 + wv*32 + hh*16 + l15,  nt = hh*4 + g,  n_p = wv*128 + nt*16 + l15
// Fragment element j of (kt, n_p, q) <-> K-row k = kt*32 + q*8 + j (the
// verified bf16 16x16x32 B-layout; i8 16x16x32 uses the same 8-contiguous-K
// per-lane mapping — verified by round-5 passing at absmax 0.0039).

// Per-column absmax scales + int8 quantization of Uh (K=256 -> 8 k-tiles).
__global__ void scales_k(const void* Uh, const void* bvec, char* Up,
                         float* Su_c, float* Bb_c, const int* dt){
  int isf32 = *dt;
  int col = blockIdx.x * blockDim.x + threadIdx.x;
  if (col >= 1024) return;
  float su = 1e-20f;
  for (int k = 0; k < 256; ++k)
    su = fmaxf(su, fabsf(load_f(Uh, (long)k*Gn + col, isf32)));
  float r = 127.f / su;
  int g = col >> 8, rem = col & 255, wv = rem >> 5, r2 = rem & 31;
  int hh = r2 >> 4, l15v = r2 & 15;
  int nt = hh*4 + g;
  int n_p = wv*128 + nt*16 + l15v;
  for (int k = 0; k < 256; ++k){
    int kt = k >> 5, q = (k >> 3) & 3, j = k & 7;
    float v = rintf(load_f(Uh, (long)k*Gn + col, isf32) * r);
    v = fminf(fmaxf(v, -127.f), 127.f);
    Up[(long)(((kt*1024 + n_p)*4 + q)*8 + j)] = (char)(int)v;
  }
  Su_c[col] = su / (127.f * 127.f);   // dequant: z_h = Su * (sum uq*hq)
  Bb_c[col] = load_f(bvec, col, isf32);
}

// Pack W (K=64 -> 2 bf16 k-tiles) into B-fragment order (streamed from L2).
__global__ void wp_k(const void* W, unsigned short* Wp, const int* dt){
  int isf32 = *dt;
  int gidx = blockIdx.x * blockDim.x + threadIdx.x;   // = (kt*1024 + n_p)*4 + q
  if (gidx >= 8192) return;
  int kt = gidx >> 12, rem = gidx & 4095, n_p = rem >> 2, q = rem & 3;
  int wv = n_p >> 7, nt = (n_p >> 4) & 7, l15v = n_p & 15;
  int col = (nt & 3)*256 + wv*32 + (nt >> 2)*16 + l15v;
  unsigned short vals[8];
  #pragma unroll
  for (int j = 0; j < 8; ++j){
    int k = kt*32 + q*8 + j;
    vals[j] = f2bf(load_f(W, (long)k*Gn + col, isf32));
  }
  *(ushort8*)(Wp + (long)gidx * 8) = *(ushort8*)vals;
}

// ---------------------------------------------------------------------------
// Persistent LSTM, 32 blocks x 512 threads (8 waves), ONE block per group.
// Rounds 0-4 proved the cross-CU h-exchange is a ~4500cy structural floor —
// eliminated: Uh int8 (per-col scales) VGPR-resident, h recurrence LDS-only,
// single barrier/step. zx(t+1) = x_{t+1}@W + b computed one step ahead in
// exact bf16 MFMA (producer C-layout == consumer layout), W streamed from L2.
// Round-6: fast-rcp gates + t-invariant Su/Bb hoisted to registers.
__global__ __launch_bounds__(THREADS, 2) void lstm_k(
    const void* x, const void* dense_w, const void* dense_b,
    const char* Up, const unsigned short* Wp,
    const float* Su_g, const float* Bb_g, const int* dt, void* out)
{
  __shared__ __align__(16) char A_s[2][16*ASB];        // h, int8, dbuf
  __shared__ __align__(16) unsigned short xs[2][16*XSW]; // x rows, bf16, dbuf
  __shared__ float outv[16];

  const int isf32 = *dt;
  const int tid = threadIdx.x;
  const int wv  = tid >> 6;       // wave 0..7 (owns 128 of 1024 z-cols)
  const int l   = tid & 63;
  const int l15 = l & 15;
  const int q   = l >> 4;
  const int gb  = blockIdx.x;     // batch group: rows gb*16..+16

  // ---- Uh int8 fragments into registers: wfh[kt][nt] (128 VGPR) ----
  long wfh[8][8];
  #pragma unroll
  for (int kt = 0; kt < 8; ++kt)
    #pragma unroll
    for (int nt = 0; nt < 8; ++nt)
      wfh[kt][nt] = *(const long*)(Up +
          (long)(((kt*1024 + wv*128 + nt*16 + l15)*4 + q)*8));

  // ---- t-invariant per-thread constants -> registers (were LDS reads) ----
  float su_r[8];   // [hh*4+gg]: dequant scale for this thread's cols
  #pragma unroll
  for (int hh = 0; hh < 2; ++hh)
    #pragma unroll
    for (int gg = 0; gg < 4; ++gg)
      su_r[hh*4 + gg] = Su_g[gg*256 + wv*32 + hh*16 + l15];
  float bb_r[8];   // [nt]: bias for accz init
  #pragma unroll
  for (int nt = 0; nt < 8; ++nt)
    bb_r[nt] = Bb_g[(nt & 3)*256 + wv*32 + (nt >> 2)*16 + l15];

  // ---- prologue: zero h buffer 0, stage x(0), x(1) ----
  for (int i = tid; i < 16*ASB; i += THREADS) A_s[0][i] = 0;
  for (int tt = 0; tt < 2; ++tt){
    if (tid < 128){
      int m = tid >> 3, seg = tid & 7;
      long src = ((long)(gb*16 + m)*Tn + tt)*Fn + seg*8;
      unsigned short v[8];
      if (isf32){ for (int j = 0; j < 8; ++j) v[j] = f2bf(((const float*)x)[src + j]); }
      else      { *(ushort8*)v = *(const ushort8*)((const unsigned short*)x + src); }
      *(ushort8*)&xs[tt][m*XSW + seg*8] = *(ushort8*)v;
    }
  }
  __syncthreads();

  // ---- zx(0) = x_0 @ W + b (bias folded into acc init) ----
  f32x4 accz[8];
  #pragma unroll
  for (int nt = 0; nt < 8; ++nt)
    accz[nt] = (f32x4){bb_r[nt], bb_r[nt], bb_r[nt], bb_r[nt]};
  #pragma unroll
  for (int kt2 = 0; kt2 < 2; ++kt2){
    bf16x8 afx = *(const bf16x8*)&xs[0][l15*XSW + kt2*32 + q*8];
    #pragma unroll
    for (int nt = 0; nt < 8; ++nt){
      bf16x8 wfx = *(const bf16x8*)(Wp +
          (long)(((kt2*1024 + wv*128 + nt*16 + l15)*4 + q)*8));
      accz[nt] = __builtin_amdgcn_mfma_f32_16x16x32_bf16(afx, wfx, accz[nt], 0, 0, 0);
    }
  }

  float c_st[8] = {0.f,0.f,0.f,0.f,0.f,0.f,0.f,0.f};

  for (int t = 0; t < Tn; ++t){
    const int buf = t & 1, nbuf = buf ^ 1;

    // (1) x(t+2) global -> regs (consumed at stage (4))
    unsigned short xv[8];
    if (tid < 128 && (t+2) < Tn){
      int m = tid >> 3, seg = tid & 7;
      long src = ((long)(gb*16 + m)*Tn + (t+2))*Fn + seg*8;
      if (isf32){ for (int j = 0; j < 8; ++j) xv[j] = f2bf(((const float*)x)[src + j]); }
      else      { *(ushort8*)xv = *(const ushort8*)((const unsigned short*)x + src); }
    }

    // (2) per-hh half: int8 h-MFMA then gates (keeps live acc regs at 16)
    #pragma unroll
    for (int hh = 0; hh < 2; ++hh){
      i32x4 acch[4];
      #pragma unroll
      for (int gg = 0; gg < 4; ++gg) acch[gg] = (i32x4){0,0,0,0};
      #pragma unroll
      for (int kt = 0; kt < 8; ++kt){
        long af = *(const long*)&A_s[buf][l15*ASB + kt*32 + q*8];
        #pragma unroll
        for (int gg = 0; gg < 4; ++gg)
          acch[gg] = __builtin_amdgcn_mfma_i32_16x16x32_i8(
              af, wfh[kt][hh*4 + gg], acch[gg], 0, 0, 0);
      }
      #pragma unroll
      for (int r = 0; r < 4; ++r){
        float zi = su_r[hh*4+0]*(float)acch[0][r] + accz[hh*4 + 0][r];
        float zf = su_r[hh*4+1]*(float)acch[1][r] + accz[hh*4 + 1][r];
        float zg = su_r[hh*4+2]*(float)acch[2][r] + accz[hh*4 + 2][r];
        float zo = su_r[hh*4+3]*(float)acch[3][r] + accz[hh*4 + 3][r];
        float ig = sigm(zi), fg = sigm(zf), gt = tanh_f(zg), og = sigm(zo);
        float cn = fg*c_st[hh*4 + r] + ig*gt;
        c_st[hh*4 + r] = cn;
        float hv = og * tanh_f(cn);
        float hq = fminf(fmaxf(rintf(hv * 127.f), -127.f), 127.f);
        A_s[nbuf][(q*4 + r)*ASB + wv*32 + hh*16 + l15] = (char)(int)hq;
      }
    }

    // (3) zx(t+1) = x_{t+1} @ W + b — exact bf16, into the freed accz regs
    if (t + 1 < Tn){
      const int p = (t + 1) & 1;
      #pragma unroll
      for (int nt = 0; nt < 8; ++nt)
        accz[nt] = (f32x4){bb_r[nt], bb_r[nt], bb_r[nt], bb_r[nt]};
      #pragma unroll
      for (int kt2 = 0; kt2 < 2; ++kt2){
        bf16x8 afx = *(const bf16x8*)&xs[p][l15*XSW + kt2*32 + q*8];
        #pragma unroll
        for (int nt = 0; nt < 8; ++nt){
          bf16x8 wfx = *(const bf16x8*)(Wp +
              (long)(((kt2*1024 + wv*128 + nt*16 + l15)*4 + q)*8));
          accz[nt] = __builtin_amdgcn_mfma_f32_16x16x32_bf16(afx, wfx, accz[nt], 0, 0, 0);
        }
      }
    }

    // (4) stage x(t+2) into xs[(t+2)&1] (parity-disjoint from (3)'s reads)
    if (tid < 128 && (t+2) < Tn){
      int m = tid >> 3, seg = tid & 7;
      *(ushort8*)&xs[(t+2) & 1][m*XSW + seg*8] = *(ushort8*)xv;
    }
    __syncthreads();   // single barrier: h(t+1) + x(t+2) visible
  }

  // ---- epilogue: attention with s-dim==1 collapses to out = sigm(h_T.dw+db) ----
  {
    int m = tid >> 5, j = tid & 31;
    float partial = 0.f;
    for (int u = j; u < 256; u += 32)
      partial += (float)(int)((signed char)A_s[0][m*ASB + u]) *
                 load_f(dense_w, u, isf32);
    #pragma unroll
    for (int off = 1; off < 32; off <<= 1) partial += __shfl_xor(partial, off);
    if (j == 0)
      outv[m] = sigm(partial * (1.f/127.f) + load_f(dense_b, 0, isf32));
  }
  __syncthreads();
  for (int mm = 0; mm < 16; ++mm){
    float v = outv[mm];
    long base = (long)(gb*16 + mm) * Tn;
    for (int col2 = tid; col2 < Tn; col2 += THREADS){
      if (isf32) ((float*)out)[base + col2] = v;
      else       ((unsigned short*)out)[base + col2] = f2bf(v);
    }
  }
}

// ---------------------------------------------------------------------------
extern "C" void kernel_launch(void* const* d_in, const int* in_sizes, int n_in,
                              void* d_out, int out_size, void* d_ws, size_t ws_size,
                              hipStream_t stream){
  const void* x  = d_in[0];
  const void* W  = d_in[1];
  const void* Uh = d_in[2];
  const void* b  = d_in[3];
  const void* dw = d_in[4];
  const void* db = d_in[5];

  int* hdr = (int*)d_ws;
  char* Up = (char*)d_ws + WS_UP;
  unsigned short* Wp = (unsigned short*)((char*)d_ws + WS_WP);
  float* Su = (float*)((char*)d_ws + WS_SU);
  float* Bb = (float*)((char*)d_ws + WS_BB);

  init_k<<<1, 64, 0, stream>>>(x, hdr);
  scales_k<<<4, 256, 0, stream>>>(Uh, b, Up, Su, Bb, hdr);
  wp_k<<<32, 256, 0, stream>>>(W, Wp, hdr);
  lstm_k<<<NB, THREADS, 0, stream>>>(x, dw, db, Up, Wp, Su, Bb, hdr, d_out);
}